// Round 30
// baseline (311.379 us; speedup 1.0000x reference)
//
#include <hip/hip_runtime.h>

// ---------------------------------------------------------------------------
// AttentionLayer (weight-norm in/out proj + softmax cross-attention)
// N=16, TQ=TS=C=E=1024, fp32 in/out.
//
// FINAL (confirmed 7x: 307.5/306.7/310.5/310.1/308.4/306.3/309.9 us).
// Single-pass f16 MFMA GEMMs (softmax Jacobian <= 0.25 bounds attn err;
// absmax 1.375 vs threshold 2.8, stable across 16 runs). GEMM1 stages f32 x
// directly (2-plane parity-split LDS, measured 0-conflict); GEMM2/3/4 pure
// f16. GEMM core: 256x128 tile, 8 waves, BK=32, dbuf LDS, 2 blocks/CU,
// drain-0 2-phase loop (best of the measured {drain0,counted} x {1,2 blk}
// x BK{32,64} x 3-tile-shape matrix). Aux: merged wnorm / merged transpose
// / fused softmax(+at16).
//
// Memory plan (ws 68MB):
//   ws:  [0,2) Wi16  [2,4) Wo16  [4,36) VT16  [36,68) KT16 -> ctx16
//   d_out [0,32):  at16 (softmax out, dead after GEMM3) -> out(lo, GEMM4)
//   d_out [32,64): h16 (dead after GEMM2) -> out(hi, GEMM4)
//   d_out [64,128): scores f32 -> attn f32 (softmax in-place, final output)
// Inputs never written.
// ---------------------------------------------------------------------------

typedef _Float16 f16_t;
typedef f16_t f16x8 __attribute__((ext_vector_type(8)));
typedef f16_t f16x4 __attribute__((ext_vector_type(4)));
typedef float f32x4 __attribute__((ext_vector_type(4)));

constexpr int BM = 256, BN = 128, BK = 32;
#define SQRT_HALF 0.7071067811865476f

__device__ __forceinline__ void stage16(const void* g, void* lds) {
  __builtin_amdgcn_global_load_lds(
      (const __attribute__((address_space(1))) unsigned int*)g,
      (__attribute__((address_space(3))) unsigned int*)lds, 16, 0, 0);
}

// ---------------- weight norm (dim=0), both matrices in one launch ---------
__global__ __launch_bounds__(256) void wnorm_both_kernel(
    const float* __restrict__ v1, const float* __restrict__ g1,
    f16_t* __restrict__ o1,
    const float* __restrict__ v2, const float* __restrict__ g2,
    f16_t* __restrict__ o2, int C)
{
  int row = blockIdx.x;
  const float* vr;
  f16_t* o;
  float gv;
  if (row < 1024) { vr = v1 + (long)row * C;          o = o1 + (long)row * C;          gv = g1[row]; }
  else            { vr = v2 + (long)(row - 1024) * C; o = o2 + (long)(row - 1024) * C; gv = g2[row - 1024]; }
  float ss = 0.f;
  for (int c = threadIdx.x; c < C; c += 256) { float x = vr[c]; ss += x * x; }
#pragma unroll
  for (int m = 1; m < 64; m <<= 1) ss += __shfl_xor(ss, m, 64);
  __shared__ float red[4];
  if ((threadIdx.x & 63) == 0) red[threadIdx.x >> 6] = ss;
  __syncthreads();
  float tot = red[0] + red[1] + red[2] + red[3];
  float scale = gv / sqrtf(tot);
  for (int c = threadIdx.x; c < C; c += 256)
    o[c] = (f16_t)(vr[c] * scale);
}

// ------ transpose f32 -> f16 for BOTH ek->KT and ev->VT in one launch ------
__global__ __launch_bounds__(256) void transpose_both_kernel(
    const float* __restrict__ in1, f16_t* __restrict__ o1,
    const float* __restrict__ in2, f16_t* __restrict__ o2, int R, int C)
{
  __shared__ float t[32][33];
  int z = blockIdx.z;
  const float* in;
  f16_t* o;
  long zb;
  if (z < 16) { in = in1; o = o1; zb = (long)z * R * C; }
  else        { in = in2; o = o2; zb = (long)(z - 16) * R * C; }
  int r0 = blockIdx.y * 32, c0 = blockIdx.x * 32;
  int tx = threadIdx.x & 31, ty = threadIdx.x >> 5;
#pragma unroll
  for (int i = 0; i < 4; ++i)
    t[ty + i * 8][tx] = in[zb + (long)(r0 + ty + i * 8) * C + c0 + tx];
  __syncthreads();
#pragma unroll
  for (int i = 0; i < 4; ++i) {
    int oc = ty + i * 8;
    o[zb + (long)(c0 + oc) * R + r0 + tx] = (f16_t)t[tx][oc];
  }
}

// --------------------------- GEMM 256x128 ----------------------------------
// C[M][Nn] = A[M][K] * Bt[Nn][K]^T. 512 threads, 8 waves (4 row x 2 col),
// per-wave output 64x64 (4mf x 4nf of 16x16x32 MFMA). BK=32. Drain-0 2-phase
// loop: STAGE(next) -> COMPUTE(cur) -> vmcnt(0) -> s_barrier.
//
// A, AF32=false: f16 [M][K]; 64B rows, 4 chunks, key (row>>1)&3 (0-conflict).
// A, AF32=true:  f32 [M][K]; two 16KB planes by chunk parity (measured
//   0-conflict): LDS (b,row,P) = global chunk 2*(P^((row>>1)&3))+b.
//   Fragment = one b128 per plane; cvt f32->f16 in-register (RNE).
// B: always f16, 8KB/buffer, proven 4-chunk swizzle.
// EPI 0: h   = (acc + bias[col] + addt[gi]) * scale -> f16 outH
// EPI 1: scores = acc                               -> f32 outF (batched)
// EPI 2: ctx = acc * scale                          -> f16 outH (batched)
// EPI 3: out = (acc + bias[col] + addt[gi]) * scale -> f32 outF
template <int EPI, bool AF32>
__global__ __launch_bounds__(512) void gemm_f16_kernel(
    const void* __restrict__ Ap, const f16_t* __restrict__ B,
    int K, long sAb, long sBb,
    const float* __restrict__ bias, const float* __restrict__ addt,
    float scale, float* __restrict__ outF, f16_t* __restrict__ outH,
    long sOb, int Nn)
{
  const int n = blockIdx.z;
  B += (long)n * sBb;
  const long ob = (long)n * sOb;

  const int row0 = blockIdx.x * BM, col0 = blockIdx.y * BN;
  const int tid = threadIdx.x;
  const int l = tid & 63;
  const int w = tid >> 6;
  const int wr = w >> 1, wc = w & 1;          // 4x2 wave grid
  const int lr = l & 15, lq = l >> 4;

  constexpr int ABYTES = (AF32 ? 4 : 2) * BM * BK;   // per half-buffer
  __shared__ __align__(16) char AshRaw[2 * ABYTES];  // 64KB or 32KB
  __shared__ __align__(16) f16_t Bsh[2 * BN * BK];   // 16KB

  // ---- B staging geometry (f16, 4 chunks/row, key (row>>1)&3) ----
  const int srowB = tid >> 2;                             // 0..127
  const int scolB = 8 * ((tid & 3) ^ ((srowB >> 1) & 3)); // f16 elems
  const int wbase = (tid * 16) & ~1023;                   // wave-uniform base
  const long bbase = (long)(col0 + srowB) * K + scolB;

  // ---- A staging geometry ----
  const f16_t* A16 = nullptr;
  const float* A32 = nullptr;
  long abase = 0;
  if constexpr (AF32) {
    A32 = (const float*)Ap + (long)n * sAb;
    const int srowA = tid >> 2;                           // 0..127
    const int keyA = (tid >> 3) & 3;                      // (row>>1)&3
    const int scolA = 8 * ((tid & 3) ^ keyA);             // f32 elems (plane 0)
    abase = (long)(row0 + srowA) * K + scolA;
  } else {
    A16 = (const f16_t*)Ap + (long)n * sAb;
    abase = (long)(row0 + srowB) * K + scolB;
  }

  const int fkey = (lr >> 1) & 3;
  const int fcolB = (lq ^ fkey) * 8;

  f32x4 acc[4][4] = {};

  auto STAGE = [&](int half, int k0) {
    char* ab = AshRaw + half * ABYTES;
    char* bb = (char*)Bsh + half * 8192;
    if constexpr (AF32) {
      const long rstep = 128L * (long)K;                  // +128 rows
      stage16(A32 + abase + k0,             ab + wbase);          // b0 r0
      stage16(A32 + abase + rstep + k0,     ab + 8192 + wbase);   // b0 r+128
      stage16(A32 + abase + 4 + k0,         ab + 16384 + wbase);  // b1 r0
      stage16(A32 + abase + rstep + 4 + k0, ab + 24576 + wbase);  // b1 r+128
    } else {
      const long rstep = 128L * (long)K;
      stage16(A16 + abase + k0, ab + wbase);
      stage16(A16 + abase + rstep + k0, ab + 8192 + wbase);
    }
    stage16(B + bbase + k0, bb + wbase);
  };

  auto COMPUTE = [&](int half) {
    const char* ab = AshRaw + half * ABYTES;
    const int heB = half * BN * BK;
    f16x8 af[4], bf[4];
#pragma unroll
    for (int mf = 0; mf < 4; ++mf) {
      const int ar = wr * 64 + mf * 16 + lr;
      if constexpr (AF32) {
        const int offA = ar * 64 + (lq ^ fkey) * 16;      // proven pattern
        f32x4 a0 = *reinterpret_cast<const f32x4*>(ab + offA);          // plane0
        f32x4 a1 = *reinterpret_cast<const f32x4*>(ab + 16384 + offA);  // plane1
        f16x8 v;
        v[0] = (f16_t)a0[0]; v[1] = (f16_t)a0[1];
        v[2] = (f16_t)a0[2]; v[3] = (f16_t)a0[3];
        v[4] = (f16_t)a1[0]; v[5] = (f16_t)a1[1];
        v[6] = (f16_t)a1[2]; v[7] = (f16_t)a1[3];
        af[mf] = v;
      } else {
        const int fcolA = (lq ^ fkey) * 8;
        af[mf] = *reinterpret_cast<const f16x8*>(ab + (ar * BK + fcolA) * 2);
      }
    }
#pragma unroll
    for (int nf = 0; nf < 4; ++nf)
      bf[nf] = *reinterpret_cast<const f16x8*>(
          &Bsh[heB + (wc * 64 + nf * 16 + lr) * BK + fcolB]);
    __builtin_amdgcn_s_setprio(1);
#pragma unroll
    for (int mf = 0; mf < 4; ++mf)
#pragma unroll
      for (int nf = 0; nf < 4; ++nf)
        acc[mf][nf] = __builtin_amdgcn_mfma_f32_16x16x32_f16(
            af[mf], bf[nf], acc[mf][nf], 0, 0, 0);
    __builtin_amdgcn_s_setprio(0);
  };

  // prologue: stage tile 0, drain, publish
  STAGE(0, 0);
  asm volatile("s_waitcnt vmcnt(0)" ::: "memory");
  __builtin_amdgcn_s_barrier();
  asm volatile("" ::: "memory");

  int cur = 0;
  const int nt = K / BK;
  for (int t = 0; t < nt - 1; ++t) {
    STAGE(cur ^ 1, (t + 1) * BK);   // issue next-tile loads first
    COMPUTE(cur);
    asm volatile("s_waitcnt vmcnt(0)" ::: "memory");
    __builtin_amdgcn_s_barrier();
    asm volatile("" ::: "memory");
    cur ^= 1;
  }
  COMPUTE(cur);

#pragma unroll
  for (int mf = 0; mf < 4; ++mf)
#pragma unroll
    for (int nf = 0; nf < 4; ++nf)
#pragma unroll
      for (int r = 0; r < 4; ++r) {
        int row = row0 + wr * 64 + mf * 16 + lq * 4 + r;  // C/D: row=(l>>4)*4+r
        int col = col0 + wc * 64 + nf * 16 + lr;          //      col=l&15
        long gi = (long)row * Nn + col;
        float v = acc[mf][nf][r];
        if constexpr (EPI == 0) {
          outH[gi] = (f16_t)((v + bias[col] + addt[gi]) * scale);
        } else if constexpr (EPI == 1) {
          outF[ob + gi] = v;
        } else if constexpr (EPI == 2) {
          outH[ob + gi] = (f16_t)(v * scale);
        } else {
          outF[gi] = (v + bias[col] + addt[gi]) * scale;
        }
      }
}

// ------- softmax (rows of 1024): in-place f32 + f16 copy -------------------
__global__ __launch_bounds__(256) void softmax_kernel(
    float* __restrict__ sc, f16_t* __restrict__ ah)
{
  long row = blockIdx.x;
  float* p = sc + row * 1024;
  int t = threadIdx.x;
  float4 v = reinterpret_cast<float4*>(p)[t];
  float m = fmaxf(fmaxf(v.x, v.y), fmaxf(v.z, v.w));
#pragma unroll
  for (int mask = 1; mask < 64; mask <<= 1) m = fmaxf(m, __shfl_xor(m, mask, 64));
  __shared__ float red[4], red2[4];
  if ((t & 63) == 0) red[t >> 6] = m;
  __syncthreads();
  m = fmaxf(fmaxf(red[0], red[1]), fmaxf(red[2], red[3]));
  float e0 = expf(v.x - m), e1 = expf(v.y - m);
  float e2 = expf(v.z - m), e3 = expf(v.w - m);
  float s = e0 + e1 + e2 + e3;
#pragma unroll
  for (int mask = 1; mask < 64; mask <<= 1) s += __shfl_xor(s, mask, 64);
  if ((t & 63) == 0) red2[t >> 6] = s;
  __syncthreads();
  s = red2[0] + red2[1] + red2[2] + red2[3];
  float inv = 1.f / s;
  float a0 = e0 * inv, a1 = e1 * inv, a2 = e2 * inv, a3 = e3 * inv;
  reinterpret_cast<float4*>(p)[t] = make_float4(a0, a1, a2, a3);
  f16x4 hv;
  hv[0] = (f16_t)a0; hv[1] = (f16_t)a1; hv[2] = (f16_t)a2; hv[3] = (f16_t)a3;
  *reinterpret_cast<f16x4*>(&ah[row * 1024 + (long)t * 4]) = hv;
}

// ---------------------------------------------------------------------------
extern "C" void kernel_launch(void* const* d_in, const int* in_sizes, int n_in,
                              void* d_out, int out_size, void* d_ws, size_t ws_size,
                              hipStream_t stream)
{
  (void)in_sizes; (void)n_in; (void)out_size; (void)ws_size;
  const float* x   = (const float*)d_in[0];
  const float* te  = (const float*)d_in[1];
  const float* ek  = (const float*)d_in[2];
  const float* ev  = (const float*)d_in[3];
  const float* ipv = (const float*)d_in[4];
  const float* ipg = (const float*)d_in[5];
  const float* ipb = (const float*)d_in[6];
  const float* opv = (const float*)d_in[7];
  const float* opg = (const float*)d_in[8];
  const float* opb = (const float*)d_in[9];

  const long M1 = 1024L * 1024L;
  float* out   = (float*)d_out;                       // [16,1024,1024] final out
  float* attnF = out + 16 * M1;                       // [16,1024,1024] final attn

  // ws (68MB total)
  char* ws = (char*)d_ws;
  f16_t* Wi16  = (f16_t*)(ws);                        // [0,2)
  f16_t* Wo16  = (f16_t*)(ws + (2L << 20));           // [2,4)
  f16_t* VT16  = (f16_t*)(ws + (4L << 20));           // [4,36)
  f16_t* KT16  = (f16_t*)(ws + (36L << 20));          // [36,68)
  f16_t* ctx16 = KT16;                                // reuse (KT dead after GEMM2)

  // d_out scratch
  f16_t* at16 = (f16_t*)d_out;                        // [0,32MB), dead after GEMM3
  f16_t* h16 = (f16_t*)d_out + 16 * M1;               // [32,64MB), dead after GEMM2
  float* scores = attnF;                              // [64,128MB), in-place softmax

  // 1. weight norm (both) -> f16
  wnorm_both_kernel<<<dim3(2048), dim3(256), 0, stream>>>(
      ipv, ipg, Wi16, opv, opg, Wo16, 1024);
  // 2. transposes (both): KT[n][s][e] = ek[n][e][s]; VT[n][e][s] = ev[n][s][e]
  transpose_both_kernel<<<dim3(32, 32, 32), dim3(256), 0, stream>>>(
      ek, KT16, ev, VT16, 1024, 1024);
  // 3. GEMM1: h = (x @ Wi^T + b + te) * sqrt(.5) -> f16 d_out[32,64) (A=x f32)
  gemm_f16_kernel<0, true><<<dim3(64, 8, 1), dim3(512), 0, stream>>>(
      x, Wi16, 1024, 0L, 0L, ipb, te, SQRT_HALF, nullptr, h16, 0L, 1024);
  // 4. GEMM2: scores = h @ K -> f32 d_out[64,128)
  gemm_f16_kernel<1, false><<<dim3(4, 8, 16), dim3(512), 0, stream>>>(
      h16, KT16, 1024, M1, M1, nullptr, nullptr, 1.0f, scores, nullptr, M1, 1024);
  // 5. softmax in-place -> attn f32 (final) + at16 f16 (d_out[0,32))
  softmax_kernel<<<dim3(16384), dim3(256), 0, stream>>>(scores, at16);
  // 6. GEMM3: ctx = (at16 @ V) * 32 -> f16 ws (A=f16; KT dead)
  gemm_f16_kernel<2, false><<<dim3(4, 8, 16), dim3(512), 0, stream>>>(
      at16, VT16, 1024, M1, M1, nullptr, nullptr, 32.0f, nullptr, ctx16, M1, 1024);
  // 7. GEMM4: out = (ctx16 @ Wo^T + b + x) * sqrt(.5) -> f32 d_out[0,64)
  gemm_f16_kernel<3, false><<<dim3(64, 8, 1), dim3(512), 0, stream>>>(
      ctx16, Wo16, 1024, 0L, 0L, opb, x, SQRT_HALF, out, nullptr, 0L, 1024);
}

// Round 31
// 305.463 us; speedup vs baseline: 1.0194x; 1.0194x over previous
//
#include <hip/hip_runtime.h>

// ---------------------------------------------------------------------------
// AttentionLayer (weight-norm in/out proj + softmax cross-attention)
// N=16, TQ=TS=C=E=1024, fp32 in/out.
//
// FINAL (confirmed 8x: 307.5/306.7/310.5/310.1/308.4/306.3/309.9/311.4 us).
// Single-pass f16 MFMA GEMMs (softmax Jacobian <= 0.25 bounds attn err;
// absmax 1.375 vs threshold 2.8, stable across 17 runs). GEMM1 stages f32 x
// directly (2-plane parity-split LDS, measured 0-conflict); GEMM2/3/4 pure
// f16. GEMM core: 256x128 tile, 8 waves, BK=32, dbuf LDS, 2 blocks/CU,
// drain-0 2-phase loop (best of the measured {drain0,counted} x {1,2 blk}
// x BK{32,64} x 3-tile-shape matrix). Aux: merged wnorm / merged transpose
// / fused softmax(+at16).
//
// Memory plan (ws 68MB):
//   ws:  [0,2) Wi16  [2,4) Wo16  [4,36) VT16  [36,68) KT16 -> ctx16
//   d_out [0,32):  at16 (softmax out, dead after GEMM3) -> out(lo, GEMM4)
//   d_out [32,64): h16 (dead after GEMM2) -> out(hi, GEMM4)
//   d_out [64,128): scores f32 -> attn f32 (softmax in-place, final output)
// Inputs never written.
// ---------------------------------------------------------------------------

typedef _Float16 f16_t;
typedef f16_t f16x8 __attribute__((ext_vector_type(8)));
typedef f16_t f16x4 __attribute__((ext_vector_type(4)));
typedef float f32x4 __attribute__((ext_vector_type(4)));

constexpr int BM = 256, BN = 128, BK = 32;
#define SQRT_HALF 0.7071067811865476f

__device__ __forceinline__ void stage16(const void* g, void* lds) {
  __builtin_amdgcn_global_load_lds(
      (const __attribute__((address_space(1))) unsigned int*)g,
      (__attribute__((address_space(3))) unsigned int*)lds, 16, 0, 0);
}

// ---------------- weight norm (dim=0), both matrices in one launch ---------
__global__ __launch_bounds__(256) void wnorm_both_kernel(
    const float* __restrict__ v1, const float* __restrict__ g1,
    f16_t* __restrict__ o1,
    const float* __restrict__ v2, const float* __restrict__ g2,
    f16_t* __restrict__ o2, int C)
{
  int row = blockIdx.x;
  const float* vr;
  f16_t* o;
  float gv;
  if (row < 1024) { vr = v1 + (long)row * C;          o = o1 + (long)row * C;          gv = g1[row]; }
  else            { vr = v2 + (long)(row - 1024) * C; o = o2 + (long)(row - 1024) * C; gv = g2[row - 1024]; }
  float ss = 0.f;
  for (int c = threadIdx.x; c < C; c += 256) { float x = vr[c]; ss += x * x; }
#pragma unroll
  for (int m = 1; m < 64; m <<= 1) ss += __shfl_xor(ss, m, 64);
  __shared__ float red[4];
  if ((threadIdx.x & 63) == 0) red[threadIdx.x >> 6] = ss;
  __syncthreads();
  float tot = red[0] + red[1] + red[2] + red[3];
  float scale = gv / sqrtf(tot);
  for (int c = threadIdx.x; c < C; c += 256)
    o[c] = (f16_t)(vr[c] * scale);
}

// ------ transpose f32 -> f16 for BOTH ek->KT and ev->VT in one launch ------
__global__ __launch_bounds__(256) void transpose_both_kernel(
    const float* __restrict__ in1, f16_t* __restrict__ o1,
    const float* __restrict__ in2, f16_t* __restrict__ o2, int R, int C)
{
  __shared__ float t[32][33];
  int z = blockIdx.z;
  const float* in;
  f16_t* o;
  long zb;
  if (z < 16) { in = in1; o = o1; zb = (long)z * R * C; }
  else        { in = in2; o = o2; zb = (long)(z - 16) * R * C; }
  int r0 = blockIdx.y * 32, c0 = blockIdx.x * 32;
  int tx = threadIdx.x & 31, ty = threadIdx.x >> 5;
#pragma unroll
  for (int i = 0; i < 4; ++i)
    t[ty + i * 8][tx] = in[zb + (long)(r0 + ty + i * 8) * C + c0 + tx];
  __syncthreads();
#pragma unroll
  for (int i = 0; i < 4; ++i) {
    int oc = ty + i * 8;
    o[zb + (long)(c0 + oc) * R + r0 + tx] = (f16_t)t[tx][oc];
  }
}

// --------------------------- GEMM 256x128 ----------------------------------
// C[M][Nn] = A[M][K] * Bt[Nn][K]^T. 512 threads, 8 waves (4 row x 2 col),
// per-wave output 64x64 (4mf x 4nf of 16x16x32 MFMA). BK=32. Drain-0 2-phase
// loop: STAGE(next) -> COMPUTE(cur) -> vmcnt(0) -> s_barrier.
//
// A, AF32=false: f16 [M][K]; 64B rows, 4 chunks, key (row>>1)&3 (0-conflict).
// A, AF32=true:  f32 [M][K]; two 16KB planes by chunk parity (measured
//   0-conflict): LDS (b,row,P) = global chunk 2*(P^((row>>1)&3))+b.
//   Fragment = one b128 per plane; cvt f32->f16 in-register (RNE).
// B: always f16, 8KB/buffer, proven 4-chunk swizzle.
// EPI 0: h   = (acc + bias[col] + addt[gi]) * scale -> f16 outH
// EPI 1: scores = acc                               -> f32 outF (batched)
// EPI 2: ctx = acc * scale                          -> f16 outH (batched)
// EPI 3: out = (acc + bias[col] + addt[gi]) * scale -> f32 outF
template <int EPI, bool AF32>
__global__ __launch_bounds__(512) void gemm_f16_kernel(
    const void* __restrict__ Ap, const f16_t* __restrict__ B,
    int K, long sAb, long sBb,
    const float* __restrict__ bias, const float* __restrict__ addt,
    float scale, float* __restrict__ outF, f16_t* __restrict__ outH,
    long sOb, int Nn)
{
  const int n = blockIdx.z;
  B += (long)n * sBb;
  const long ob = (long)n * sOb;

  const int row0 = blockIdx.x * BM, col0 = blockIdx.y * BN;
  const int tid = threadIdx.x;
  const int l = tid & 63;
  const int w = tid >> 6;
  const int wr = w >> 1, wc = w & 1;          // 4x2 wave grid
  const int lr = l & 15, lq = l >> 4;

  constexpr int ABYTES = (AF32 ? 4 : 2) * BM * BK;   // per half-buffer
  __shared__ __align__(16) char AshRaw[2 * ABYTES];  // 64KB or 32KB
  __shared__ __align__(16) f16_t Bsh[2 * BN * BK];   // 16KB

  // ---- B staging geometry (f16, 4 chunks/row, key (row>>1)&3) ----
  const int srowB = tid >> 2;                             // 0..127
  const int scolB = 8 * ((tid & 3) ^ ((srowB >> 1) & 3)); // f16 elems
  const int wbase = (tid * 16) & ~1023;                   // wave-uniform base
  const long bbase = (long)(col0 + srowB) * K + scolB;

  // ---- A staging geometry ----
  const f16_t* A16 = nullptr;
  const float* A32 = nullptr;
  long abase = 0;
  if constexpr (AF32) {
    A32 = (const float*)Ap + (long)n * sAb;
    const int srowA = tid >> 2;                           // 0..127
    const int keyA = (tid >> 3) & 3;                      // (row>>1)&3
    const int scolA = 8 * ((tid & 3) ^ keyA);             // f32 elems (plane 0)
    abase = (long)(row0 + srowA) * K + scolA;
  } else {
    A16 = (const f16_t*)Ap + (long)n * sAb;
    abase = (long)(row0 + srowB) * K + scolB;
  }

  const int fkey = (lr >> 1) & 3;
  const int fcolB = (lq ^ fkey) * 8;

  f32x4 acc[4][4] = {};

  auto STAGE = [&](int half, int k0) {
    char* ab = AshRaw + half * ABYTES;
    char* bb = (char*)Bsh + half * 8192;
    if constexpr (AF32) {
      const long rstep = 128L * (long)K;                  // +128 rows
      stage16(A32 + abase + k0,             ab + wbase);          // b0 r0
      stage16(A32 + abase + rstep + k0,     ab + 8192 + wbase);   // b0 r+128
      stage16(A32 + abase + 4 + k0,         ab + 16384 + wbase);  // b1 r0
      stage16(A32 + abase + rstep + 4 + k0, ab + 24576 + wbase);  // b1 r+128
    } else {
      const long rstep = 128L * (long)K;
      stage16(A16 + abase + k0, ab + wbase);
      stage16(A16 + abase + rstep + k0, ab + 8192 + wbase);
    }
    stage16(B + bbase + k0, bb + wbase);
  };

  auto COMPUTE = [&](int half) {
    const char* ab = AshRaw + half * ABYTES;
    const int heB = half * BN * BK;
    f16x8 af[4], bf[4];
#pragma unroll
    for (int mf = 0; mf < 4; ++mf) {
      const int ar = wr * 64 + mf * 16 + lr;
      if constexpr (AF32) {
        const int offA = ar * 64 + (lq ^ fkey) * 16;      // proven pattern
        f32x4 a0 = *reinterpret_cast<const f32x4*>(ab + offA);          // plane0
        f32x4 a1 = *reinterpret_cast<const f32x4*>(ab + 16384 + offA);  // plane1
        f16x8 v;
        v[0] = (f16_t)a0[0]; v[1] = (f16_t)a0[1];
        v[2] = (f16_t)a0[2]; v[3] = (f16_t)a0[3];
        v[4] = (f16_t)a1[0]; v[5] = (f16_t)a1[1];
        v[6] = (f16_t)a1[2]; v[7] = (f16_t)a1[3];
        af[mf] = v;
      } else {
        const int fcolA = (lq ^ fkey) * 8;
        af[mf] = *reinterpret_cast<const f16x8*>(ab + (ar * BK + fcolA) * 2);
      }
    }
#pragma unroll
    for (int nf = 0; nf < 4; ++nf)
      bf[nf] = *reinterpret_cast<const f16x8*>(
          &Bsh[heB + (wc * 64 + nf * 16 + lr) * BK + fcolB]);
    __builtin_amdgcn_s_setprio(1);
#pragma unroll
    for (int mf = 0; mf < 4; ++mf)
#pragma unroll
      for (int nf = 0; nf < 4; ++nf)
        acc[mf][nf] = __builtin_amdgcn_mfma_f32_16x16x32_f16(
            af[mf], bf[nf], acc[mf][nf], 0, 0, 0);
    __builtin_amdgcn_s_setprio(0);
  };

  // prologue: stage tile 0, drain, publish
  STAGE(0, 0);
  asm volatile("s_waitcnt vmcnt(0)" ::: "memory");
  __builtin_amdgcn_s_barrier();
  asm volatile("" ::: "memory");

  int cur = 0;
  const int nt = K / BK;
  for (int t = 0; t < nt - 1; ++t) {
    STAGE(cur ^ 1, (t + 1) * BK);   // issue next-tile loads first
    COMPUTE(cur);
    asm volatile("s_waitcnt vmcnt(0)" ::: "memory");
    __builtin_amdgcn_s_barrier();
    asm volatile("" ::: "memory");
    cur ^= 1;
  }
  COMPUTE(cur);

#pragma unroll
  for (int mf = 0; mf < 4; ++mf)
#pragma unroll
    for (int nf = 0; nf < 4; ++nf)
#pragma unroll
      for (int r = 0; r < 4; ++r) {
        int row = row0 + wr * 64 + mf * 16 + lq * 4 + r;  // C/D: row=(l>>4)*4+r
        int col = col0 + wc * 64 + nf * 16 + lr;          //      col=l&15
        long gi = (long)row * Nn + col;
        float v = acc[mf][nf][r];
        if constexpr (EPI == 0) {
          outH[gi] = (f16_t)((v + bias[col] + addt[gi]) * scale);
        } else if constexpr (EPI == 1) {
          outF[ob + gi] = v;
        } else if constexpr (EPI == 2) {
          outH[ob + gi] = (f16_t)(v * scale);
        } else {
          outF[gi] = (v + bias[col] + addt[gi]) * scale;
        }
      }
}

// ------- softmax (rows of 1024): in-place f32 + f16 copy -------------------
__global__ __launch_bounds__(256) void softmax_kernel(
    float* __restrict__ sc, f16_t* __restrict__ ah)
{
  long row = blockIdx.x;
  float* p = sc + row * 1024;
  int t = threadIdx.x;
  float4 v = reinterpret_cast<float4*>(p)[t];
  float m = fmaxf(fmaxf(v.x, v.y), fmaxf(v.z, v.w));
#pragma unroll
  for (int mask = 1; mask < 64; mask <<= 1) m = fmaxf(m, __shfl_xor(m, mask, 64));
  __shared__ float red[4], red2[4];
  if ((t & 63) == 0) red[t >> 6] = m;
  __syncthreads();
  m = fmaxf(fmaxf(red[0], red[1]), fmaxf(red[2], red[3]));
  float e0 = expf(v.x - m), e1 = expf(v.y - m);
  float e2 = expf(v.z - m), e3 = expf(v.w - m);
  float s = e0 + e1 + e2 + e3;
#pragma unroll
  for (int mask = 1; mask < 64; mask <<= 1) s += __shfl_xor(s, mask, 64);
  if ((t & 63) == 0) red2[t >> 6] = s;
  __syncthreads();
  s = red2[0] + red2[1] + red2[2] + red2[3];
  float inv = 1.f / s;
  float a0 = e0 * inv, a1 = e1 * inv, a2 = e2 * inv, a3 = e3 * inv;
  reinterpret_cast<float4*>(p)[t] = make_float4(a0, a1, a2, a3);
  f16x4 hv;
  hv[0] = (f16_t)a0; hv[1] = (f16_t)a1; hv[2] = (f16_t)a2; hv[3] = (f16_t)a3;
  *reinterpret_cast<f16x4*>(&ah[row * 1024 + (long)t * 4]) = hv;
}

// ---------------------------------------------------------------------------
extern "C" void kernel_launch(void* const* d_in, const int* in_sizes, int n_in,
                              void* d_out, int out_size, void* d_ws, size_t ws_size,
                              hipStream_t stream)
{
  (void)in_sizes; (void)n_in; (void)out_size; (void)ws_size;
  const float* x   = (const float*)d_in[0];
  const float* te  = (const float*)d_in[1];
  const float* ek  = (const float*)d_in[2];
  const float* ev  = (const float*)d_in[3];
  const float* ipv = (const float*)d_in[4];
  const float* ipg = (const float*)d_in[5];
  const float* ipb = (const float*)d_in[6];
  const float* opv = (const float*)d_in[7];
  const float* opg = (const float*)d_in[8];
  const float* opb = (const float*)d_in[9];

  const long M1 = 1024L * 1024L;
  float* out   = (float*)d_out;                       // [16,1024,1024] final out
  float* attnF = out + 16 * M1;                       // [16,1024,1024] final attn

  // ws (68MB total)
  char* ws = (char*)d_ws;
  f16_t* Wi16  = (f16_t*)(ws);                        // [0,2)
  f16_t* Wo16  = (f16_t*)(ws + (2L << 20));           // [2,4)
  f16_t* VT16  = (f16_t*)(ws + (4L << 20));           // [4,36)
  f16_t* KT16  = (f16_t*)(ws + (36L << 20));          // [36,68)
  f16_t* ctx16 = KT16;                                // reuse (KT dead after GEMM2)

  // d_out scratch
  f16_t* at16 = (f16_t*)d_out;                        // [0,32MB), dead after GEMM3
  f16_t* h16 = (f16_t*)d_out + 16 * M1;               // [32,64MB), dead after GEMM2
  float* scores = attnF;                              // [64,128MB), in-place softmax

  // 1. weight norm (both) -> f16
  wnorm_both_kernel<<<dim3(2048), dim3(256), 0, stream>>>(
      ipv, ipg, Wi16, opv, opg, Wo16, 1024);
  // 2. transposes (both): KT[n][s][e] = ek[n][e][s]; VT[n][e][s] = ev[n][s][e]
  transpose_both_kernel<<<dim3(32, 32, 32), dim3(256), 0, stream>>>(
      ek, KT16, ev, VT16, 1024, 1024);
  // 3. GEMM1: h = (x @ Wi^T + b + te) * sqrt(.5) -> f16 d_out[32,64) (A=x f32)
  gemm_f16_kernel<0, true><<<dim3(64, 8, 1), dim3(512), 0, stream>>>(
      x, Wi16, 1024, 0L, 0L, ipb, te, SQRT_HALF, nullptr, h16, 0L, 1024);
  // 4. GEMM2: scores = h @ K -> f32 d_out[64,128)
  gemm_f16_kernel<1, false><<<dim3(4, 8, 16), dim3(512), 0, stream>>>(
      h16, KT16, 1024, M1, M1, nullptr, nullptr, 1.0f, scores, nullptr, M1, 1024);
  // 5. softmax in-place -> attn f32 (final) + at16 f16 (d_out[0,32))
  softmax_kernel<<<dim3(16384), dim3(256), 0, stream>>>(scores, at16);
  // 6. GEMM3: ctx = (at16 @ V) * 32 -> f16 ws (A=f16; KT dead)
  gemm_f16_kernel<2, false><<<dim3(4, 8, 16), dim3(512), 0, stream>>>(
      at16, VT16, 1024, M1, M1, nullptr, nullptr, 32.0f, nullptr, ctx16, M1, 1024);
  // 7. GEMM4: out = (ctx16 @ Wo^T + b + x) * sqrt(.5) -> f32 d_out[0,64)
  gemm_f16_kernel<3, false><<<dim3(64, 8, 1), dim3(512), 0, stream>>>(
      ctx16, Wo16, 1024, 0L, 0L, opb, x, SQRT_HALF, out, nullptr, 0L, 1024);
}